// Round 17
// baseline (83.605 us; speedup 1.0000x reference)
//
#include <hip/hip_runtime.h>
#include <stdint.h>

typedef __attribute__((ext_vector_type(8))) __bf16 bf16x8;
typedef __attribute__((ext_vector_type(4))) float f32x4;

// Selected upper-tri circular-adjacency pairs (r,c), row-major triu order. K=64.
__device__ const unsigned char dR[64] = {
  0,0,0,0,0,0,0,
  1,1,1,1,1,1,
  2,2,2,2,2,
  3,3,3,3,
  4,4,4,4,
  5,5,5,5,
  6,6,6,6,
  7,7,7,7,
  8,8,8,8,
  9,9,9,9,
  10,10,10,10,
  11,11,11,11,
  12,12,12,12,
  13,13,13,
  14,14,
  15};
__device__ const unsigned char dC[64] = {
  0,1,2,3,13,14,15,
  1,2,3,4,14,15,
  2,3,4,5,15,
  3,4,5,6,
  4,5,6,7,
  5,6,7,8,
  6,7,8,9,
  7,8,9,10,
  8,9,10,11,
  9,10,11,12,
  10,11,12,13,
  11,12,13,14,
  12,13,14,15,
  13,14,15,
  14,15,
  15};

__device__ __forceinline__ unsigned short f2bf(float x){
  unsigned u = __builtin_bit_cast(unsigned, x);
  return (unsigned short)((u + 0x7FFFu + ((u >> 16) & 1u)) >> 16);
}

__device__ __forceinline__ void gl16(const void* g, void* l){
  __builtin_amdgcn_global_load_lds((const __attribute__((address_space(1))) unsigned int*)g,
                                   (__attribute__((address_space(3))) unsigned int*)l,
                                   16, 0, 0);
}

// fp32 -> bf16 conversion + K-STEP PACKING: W1 -> [64 ks][512 col][32 k] bf16,
// W2 -> [16 ks][512 col][32 k] bf16. Contiguous 1KB per (ks, 16-col chunk).
__global__ void conv_w_kernel(const float* __restrict__ w1, const float* __restrict__ w2,
                              unsigned short* __restrict__ o1, unsigned short* __restrict__ o2){
  int i = blockIdx.x * 256 + threadIdx.x;
  if (i < 262144){                                  // W1: [512][2048] fp32, float4 idx
    float4 v = ((const float4*)w1)[i];
    ushort4 pk; pk.x=f2bf(v.x); pk.y=f2bf(v.y); pk.z=f2bf(v.z); pk.w=f2bf(v.w);
    const int col = i >> 9;
    const int kb  = (i & 511) << 2;
    const int ks  = kb >> 5, ko = kb & 31;
    ((ushort4*)o1)[(ks << 12) + (col << 3) + (ko >> 2)] = pk;
  } else {
    int j = i - 262144;
    if (j < 65536){                                 // W2: [512][512] fp32
      float4 v = ((const float4*)w2)[j];
      ushort4 pk; pk.x=f2bf(v.x); pk.y=f2bf(v.y); pk.z=f2bf(v.z); pk.w=f2bf(v.w);
      const int col = j >> 7;
      const int kb  = (j & 127) << 2;
      const int ks  = kb >> 5, ko = kb & 31;
      ((ushort4*)o2)[(ks << 12) + (col << 3) + (ko >> 2)] = pk;
    }
  }
}

// LDS: phase 1: W dbuf 2x32KB @ 0/32768 ([512 col][4 slot][16B], slot-swizzled),
//               gather A dbuf 2x6144 @ 65536/71680 ([kb4][96 row][16B]).
//      phase 2: A1 [96 row][512 h] bf16 XOR-swizzled @ [0, 98304) (aliases, post-barrier)
#define LW0 0
#define LW1 32768
#define LA0 65536
#define LA1 71680

// stage W k-step KS into buffer WBUF (wave-private 64 cols, 4 x gl16, packed source)
#define WSTAGE(WBUF, KS) do{ _Pragma("unroll") for (int i_ = 0; i_ < 4; ++i_)             \
  gl16((const char*)w1b + (((long)(KS)) << 15) + wso[i_], lds + (WBUF) + wdb[i_]); }while(0)

// issue 6 gather register loads into static slot S (parity PAR fixed per slot)
#define GISS(S, PAR, FV) do{ const float* xf_ = xb + ((long)(FV) << 16);                  \
  _Pragma("unroll") for (int o_ = 0; o_ < 3; ++o_)                                        \
  _Pragma("unroll") for (int e_ = 0; e_ < 2; ++e_)                                        \
    g##S[o_][e_] = xf_[poff[PAR][o_][e_]]; }while(0)

// cvt slot -> ds_write A-tile into buffer BUF (compiler inserts counted vmcnt for g regs)
#define CVTWR(S, BUF) do{ _Pragma("unroll") for (int o_ = 0; o_ < 3; ++o_){               \
  unsigned pv_ = (unsigned)f2bf(g##S[o_][0]) | ((unsigned)f2bf(g##S[o_][1]) << 16);       \
  *(unsigned*)(lds + (BUF) + awr + (o_ << 9)) = pv_; } }while(0)

// pipelined phase-split step: window1 = VMEM issue only (stage next-next W, gathers);
// barrier; free lgkm(0) + sched fence (rule #18); window2 = prio MFMA on PRELOADED
// frags[N] (CSET), then ds_read frags[N+1] (NSET) overlapping the matrix pipe, then
// cvt-write tile N+2; counted vmcnt close.
#define PSTEP2(CSET, NSET, RA, RW, WW, KS, DO_W, GS, GP, GF, DO_G, CS, CA, DO_C, DO_R, VN) do{ \
  if (DO_W) WSTAGE(WW, KS);                                                               \
  if (DO_G) GISS(GS, GP, GF);                                                             \
  __builtin_amdgcn_s_barrier();                                                           \
  asm volatile("s_waitcnt lgkmcnt(0)" ::: "memory");                                      \
  __builtin_amdgcn_sched_barrier(0);                                                      \
  __builtin_amdgcn_s_setprio(1);                                                          \
  _Pragma("unroll") for (int cn_ = 0; cn_ < 4; ++cn_)                                     \
  _Pragma("unroll") for (int fm_ = 0; fm_ < 6; ++fm_)                                     \
    acc[fm_][cn_] = __builtin_amdgcn_mfma_f32_16x16x32_bf16(frA##CSET[fm_], frW##CSET[cn_], acc[fm_][cn_], 0, 0, 0); \
  __builtin_amdgcn_s_setprio(0);                                                          \
  if (DO_R){                                                                              \
    _Pragma("unroll") for (int fm_ = 0; fm_ < 6; ++fm_)                                   \
      frA##NSET[fm_] = *(const bf16x8*)(lds + (RA) + ard + fm_*256);                      \
    _Pragma("unroll") for (int cn_ = 0; cn_ < 4; ++cn_)                                   \
      frW##NSET[cn_] = *(const bf16x8*)(lds + (RW) + wrd[cn_]);                           \
  }                                                                                       \
  if (DO_C) CVTWR(CS, CA);                                                                \
  asm volatile("s_waitcnt vmcnt(" #VN ") lgkmcnt(0)" ::: "memory");                       \
  __builtin_amdgcn_s_barrier();                                                           \
  asm volatile("" ::: "memory");                                                          \
}while(0)

#define A2SUB(ss, cc) do{                                                                 \
  bf16x8 a2[6];                                                                           \
  _Pragma("unroll") for (int fm = 0; fm < 6; ++fm){                                       \
    int byt = (((fm << 4) + lr) << 10) + ((ss) << 6) + (q << 4);                          \
    byt ^= (lr & 7) << 4;                                                                 \
    a2[fm] = *(const bf16x8*)(lds + byt);                                                 \
  }                                                                                       \
  _Pragma("unroll") for (int cn = 0; cn < 4; ++cn)                                        \
    _Pragma("unroll") for (int fm = 0; fm < 6; ++fm)                                      \
      acc2[fm][cn] = __builtin_amdgcn_mfma_f32_16x16x32_bf16(a2[fm], cc[cn], acc2[fm][cn], 0, 0, 0); \
}while(0)

// Block = (b, 32-t tile): 256 blocks, 512 threads (8 waves). Each wave: [96m x 64n].
__global__ __launch_bounds__(512, 2)
void fused_kernel(const float* __restrict__ x,
                  const float* __restrict__ b1v,
                  const float* __restrict__ b2v,
                  const unsigned short* __restrict__ w1b,
                  const unsigned short* __restrict__ w2b,
                  float* __restrict__ out)
{
  __shared__ char lds[98304];
  const int bid = blockIdx.x;
  const int b   = bid >> 3;
  const int t0  = (bid & 7) << 5;

  const int tid  = threadIdx.x;
  const int w    = tid >> 6;
  const int lane = tid & 63;
  const int q    = lane >> 4;
  const int lr   = lane & 15;
  const int u    = tid >> 5;          // [0,16): k-pair index for gather
  const int tt   = tid & 31;          // t within tile for gather

  // gather source offsets: k = par*32 + 2u + e
  int poff[2][3][2];
#pragma unroll
  for (int par = 0; par < 2; ++par)
#pragma unroll
    for (int e = 0; e < 2; ++e){
      const int k = par * 32 + 2 * u + e;
      const int r = dR[k], c = dC[k];
#pragma unroll
      for (int o = 0; o < 3; ++o){
        const int v = o - 1;                         // mean over o is order-free
        poff[par][o][e] = ((((r - v) & 15) << 4) | ((c - v) & 15)) << 8;
      }
    }
  const float* xb = x + (((long)b << 21) + t0 + tt);

  // A-tile: [kb4][row96][16B], kb stride 1536
  const int awr = ((u >> 2) * 1536) + (tt << 4) + ((u & 3) << 2);   // + o*512
  const int ard = q * 1536 + (lr << 4);                              // + fm*256
  // W-frag read: [col][4 slot][16B], slot = q ^ ((col>>1)&3)
  int wrd[4];
#pragma unroll
  for (int cn = 0; cn < 4; ++cn){
    const int col = (w << 6) + (cn << 4) + lr;
    wrd[cn] = col * 64 + ((q ^ ((col >> 1) & 3)) << 4);
  }
  // W stage: linear LDS dest (wave-uniform), inverse-swizzled packed global source
  int wso[4], wdb[4];
#pragma unroll
  for (int i = 0; i < 4; ++i){
    const int colb = (w << 6) + (i << 4);
    const int col  = colb + (lane >> 2);
    wso[i] = col * 64 + (((lane & 3) ^ ((col >> 1) & 3)) << 4);
    wdb[i] = colb * 64;
  }
  float b1c[4];
#pragma unroll
  for (int cn = 0; cn < 4; ++cn) b1c[cn] = b1v[(w << 6) + (cn << 4) + lr];

  f32x4 acc[6][4];
#pragma unroll
  for (int fm = 0; fm < 6; ++fm)
#pragma unroll
    for (int cn = 0; cn < 4; ++cn)
      acc[fm][cn] = f32x4{0.f, 0.f, 0.f, 0.f};

  float g0[3][2], g1[3][2];
  bf16x8 frA0[6], frA1[6], frW0[4], frW1[4];

  // ---------------- prologue ----------------
  // tile0->LA0, tile1->LA1, tile2->slot0 (flight); W0->LW0, W1->LW1; preload frags[0].
  {
    float gp[3][2];
#pragma unroll
    for (int o_ = 0; o_ < 3; ++o_)
#pragma unroll
      for (int e_ = 0; e_ < 2; ++e_)
        gp[o_][e_] = xb[poff[0][o_][e_]];          // tile 0 (f=0, par=0)
    WSTAGE(LW0, 0);
    WSTAGE(LW1, 1);
    GISS(1, 1, 0);                                 // tile 1 (f=0, par=1) -> slot1
    GISS(0, 0, 1);                                 // tile 2 (f=1, par=0) -> slot0
#pragma unroll
    for (int o_ = 0; o_ < 3; ++o_){
      unsigned pv_ = (unsigned)f2bf(gp[o_][0]) | ((unsigned)f2bf(gp[o_][1]) << 16);
      *(unsigned*)(lds + LA0 + awr + (o_ << 9)) = pv_;
    }
    CVTWR(1, LA1);                                 // tile 1 -> LA1 (auto-waits g1 + older gl16)
    asm volatile("s_waitcnt vmcnt(6) lgkmcnt(0)" ::: "memory");   // W0,W1 done; tile2 flying
    __builtin_amdgcn_s_barrier();
    asm volatile("" ::: "memory");
    // preload frags[0] (cross-wave data now visible)
#pragma unroll
    for (int fm_ = 0; fm_ < 6; ++fm_)
      frA0[fm_] = *(const bf16x8*)(lds + LA0 + ard + fm_*256);
#pragma unroll
    for (int cn_ = 0; cn_ < 4; ++cn_)
      frW0[cn_] = *(const bf16x8*)(lds + LW0 + wrd[cn_]);
    asm volatile("s_waitcnt lgkmcnt(0)" ::: "memory");   // reads done before LW0 overwrite
    __builtin_amdgcn_s_barrier();
    asm volatile("" ::: "memory");
  }

  // ---------------- phase 1: 64 pipelined phase-split steps ----------------------
  // step N: w1 {stage W(N+2)->LW[N%2], GISS tile N+3 -> slot (N+1)%2}; barrier;
  //         MFMA frags[N]; read frags[N+1] (LA/LW[(N+1)%2]); cvt tile N+2 -> LA[N%2].
#pragma unroll 1
  for (int it = 0; it < 30; ++it){
    PSTEP2(0, 1, LA1, LW1, LW0, (it << 1) + 2, 1,  1, 1, it + 1, 1,  0, LA0, 1, 1, 6); // N=2it
    PSTEP2(1, 0, LA0, LW0, LW1, (it << 1) + 3, 1,  0, 0, it + 2, 1,  1, LA1, 1, 1, 6); // N=2it+1
  }
  PSTEP2(0, 1, LA1, LW1, LW0, 62, 1,  1, 1, 31, 1,  0, LA0, 1, 1, 6);   // N=60
  PSTEP2(1, 0, LA0, LW0, LW1, 63, 1,  0, 0, 0,  0,  1, LA1, 1, 1, 0);   // N=61: cvt tile63
  PSTEP2(0, 1, LA1, LW1, LW0,  0, 0,  0, 0, 0,  0,  0, LA0, 0, 1, 0);   // N=62: read frags63
  PSTEP2(1, 0, LA0, LW0, LW1,  0, 0,  0, 0, 0,  0,  0, LA1, 0, 0, 0);   // N=63: compute only

  // ---------------- epilogue 1: bias + leaky -> A1 bf16 (XOR-swizzled) --------
#pragma unroll
  for (int cn = 0; cn < 4; ++cn){
    const int h  = (w << 6) + (cn << 4) + lr;
#pragma unroll
    for (int fm = 0; fm < 6; ++fm)
#pragma unroll
      for (int r = 0; r < 4; ++r){
        float vv = acc[fm][cn][r] + b1c[cn];
        vv = vv > 0.f ? vv : 0.01f * vv;
        const int row = (fm << 4) + (q << 2) + r;    // D row = 4*(lane>>4)+reg
        int byt = (row << 10) + (h << 1);
        byt ^= (row & 7) << 4;
        *(unsigned short*)(lds + byt) = f2bf(vv);
      }
  }
  asm volatile("s_waitcnt lgkmcnt(0)" ::: "memory");
  __builtin_amdgcn_s_barrier();
  asm volatile("" ::: "memory");

  // ---------------- phase 2: K=512 vs packed W2 (L2 reg frags), barrier-free ----
  int w2off[4];
  float b2c[4];
#pragma unroll
  for (int cn = 0; cn < 4; ++cn){
    const int col = (w << 6) + (cn << 4) + lr;
    w2off[cn] = (col << 6) + (q << 4);
    b2c[cn] = b2v[col];
  }
  const char* w2c = (const char*)w2b;
  f32x4 acc2[6][4];
#pragma unroll
  for (int fm = 0; fm < 6; ++fm)
#pragma unroll
    for (int cn = 0; cn < 4; ++cn)
      acc2[fm][cn] = f32x4{0.f, 0.f, 0.f, 0.f};

  bf16x8 c0[4], c1[4];
#pragma unroll
  for (int cn = 0; cn < 4; ++cn) c0[cn] = *(const bf16x8*)(w2c + w2off[cn]);

#pragma unroll 1
  for (int it2 = 0; it2 < 8; ++it2){
    const int s0 = it2 << 1;
#pragma unroll
    for (int cn = 0; cn < 4; ++cn)
      c1[cn] = *(const bf16x8*)(w2c + (((long)(s0 + 1)) << 15) + w2off[cn]);
    A2SUB(s0, c0);
    if (it2 < 7){
#pragma unroll
      for (int cn = 0; cn < 4; ++cn)
        c0[cn] = *(const bf16x8*)(w2c + (((long)(s0 + 2)) << 15) + w2off[cn]);
    }
    A2SUB(s0 + 1, c1);
  }

  // ---------------- epilogue 2: bias + leaky + mean(o) -> [B,H,T] -------------
#pragma unroll
  for (int cn = 0; cn < 4; ++cn){
    const int h  = (w << 6) + (cn << 4) + lr;
#pragma unroll
    for (int p = 0; p < 2; ++p){
      f32x4 ov;
#pragma unroll
      for (int r = 0; r < 4; ++r){
        float s = 0.f;
#pragma unroll
        for (int oo = 0; oo < 3; ++oo){
          float vv = acc2[oo * 2 + p][cn][r] + b2c[cn];
          vv = vv > 0.f ? vv : 0.01f * vv;
          s += vv;
        }
        ov[r] = s * (1.f / 3.f);
      }
      *(f32x4*)(out + (((long)b * 512 + h) << 8) + t0 + (p << 4) + (q << 2)) = ov;
    }
  }
}

extern "C" void kernel_launch(void* const* d_in, const int* in_sizes, int n_in,
                              void* d_out, int out_size, void* d_ws, size_t ws_size,
                              hipStream_t stream){
  const float* x  = (const float*)d_in[0];
  const float* w1 = (const float*)d_in[1];
  const float* b1 = (const float*)d_in[2];
  const float* w2 = (const float*)d_in[3];
  const float* b2 = (const float*)d_in[4];
  unsigned short* w1b = (unsigned short*)d_ws;            // packed W1: 2 MiB
  unsigned short* w2b = w1b + 512 * 2048;                 // packed W2: 0.5 MiB
  conv_w_kernel<<<1280, 256, 0, stream>>>(w1, w2, w1b, w2b);
  fused_kernel<<<256, 512, 0, stream>>>(x, b1, b2, w1b, w2b, (float*)d_out);
}

// Round 18
// 80.105 us; speedup vs baseline: 1.0437x; 1.0437x over previous
//
#include <hip/hip_runtime.h>
#include <stdint.h>

typedef __attribute__((ext_vector_type(8))) __bf16 bf16x8;
typedef __attribute__((ext_vector_type(4))) float f32x4;

// Selected upper-tri circular-adjacency pairs (r,c), row-major triu order. K=64.
__device__ const unsigned char dR[64] = {
  0,0,0,0,0,0,0,
  1,1,1,1,1,1,
  2,2,2,2,2,
  3,3,3,3,
  4,4,4,4,
  5,5,5,5,
  6,6,6,6,
  7,7,7,7,
  8,8,8,8,
  9,9,9,9,
  10,10,10,10,
  11,11,11,11,
  12,12,12,12,
  13,13,13,
  14,14,
  15};
__device__ const unsigned char dC[64] = {
  0,1,2,3,13,14,15,
  1,2,3,4,14,15,
  2,3,4,5,15,
  3,4,5,6,
  4,5,6,7,
  5,6,7,8,
  6,7,8,9,
  7,8,9,10,
  8,9,10,11,
  9,10,11,12,
  10,11,12,13,
  11,12,13,14,
  12,13,14,15,
  13,14,15,
  14,15,
  15};

__device__ __forceinline__ unsigned short f2bf(float x){
  unsigned u = __builtin_bit_cast(unsigned, x);
  return (unsigned short)((u + 0x7FFFu + ((u >> 16) & 1u)) >> 16);
}

__device__ __forceinline__ void gl16(const void* g, void* l){
  __builtin_amdgcn_global_load_lds((const __attribute__((address_space(1))) unsigned int*)g,
                                   (__attribute__((address_space(3))) unsigned int*)l,
                                   16, 0, 0);
}

// fp32 -> bf16 conversion + K-STEP PACKING: W1 -> [64 ks][512 col][32 k] bf16,
// W2 -> [16 ks][512 col][32 k] bf16. Contiguous 1KB per (ks, 16-col chunk).
__global__ void conv_w_kernel(const float* __restrict__ w1, const float* __restrict__ w2,
                              unsigned short* __restrict__ o1, unsigned short* __restrict__ o2){
  int i = blockIdx.x * 256 + threadIdx.x;
  if (i < 262144){                                  // W1: [512][2048] fp32, float4 idx
    float4 v = ((const float4*)w1)[i];
    ushort4 pk; pk.x=f2bf(v.x); pk.y=f2bf(v.y); pk.z=f2bf(v.z); pk.w=f2bf(v.w);
    const int col = i >> 9;
    const int kb  = (i & 511) << 2;
    const int ks  = kb >> 5, ko = kb & 31;
    ((ushort4*)o1)[(ks << 12) + (col << 3) + (ko >> 2)] = pk;
  } else {
    int j = i - 262144;
    if (j < 65536){                                 // W2: [512][512] fp32
      float4 v = ((const float4*)w2)[j];
      ushort4 pk; pk.x=f2bf(v.x); pk.y=f2bf(v.y); pk.z=f2bf(v.z); pk.w=f2bf(v.w);
      const int col = j >> 7;
      const int kb  = (j & 127) << 2;
      const int ks  = kb >> 5, ko = kb & 31;
      ((ushort4*)o2)[(ks << 12) + (col << 3) + (ko >> 2)] = pk;
    }
  }
}

// LDS: phase 1: W dbuf 2x32KB @ 0/32768 ([512 col][4 slot][16B], slot-swizzled),
//               gather A dbuf 2x6144 @ 65536/71680 ([kb4][96 row][16B]).
//      phase 2: A1 [96 row][512 h] bf16 XOR-swizzled @ [0, 98304) (aliases, post-barrier)
#define LW0 0
#define LW1 32768
#define LA0 65536
#define LA1 71680

// stage W k-step KS into buffer WBUF (wave-private 64 cols, 4 x gl16, packed source)
#define WSTAGE(WBUF, KS) do{ _Pragma("unroll") for (int i_ = 0; i_ < 4; ++i_)             \
  gl16((const char*)w1b + (((long)(KS)) << 15) + wso[i_], lds + (WBUF) + wdb[i_]); }while(0)

// issue 6 gather register loads into static slot S (parity PAR fixed per slot)
#define GISS(S, PAR, FV) do{ const float* xf_ = xb + ((long)(FV) << 16);                  \
  _Pragma("unroll") for (int o_ = 0; o_ < 3; ++o_)                                        \
  _Pragma("unroll") for (int e_ = 0; e_ < 2; ++e_)                                        \
    g##S[o_][e_] = xf_[poff[PAR][o_][e_]]; }while(0)

// cvt slot -> ds_write A-tile into buffer BUF (compiler inserts counted vmcnt for g regs)
#define CVTWR(S, BUF) do{ _Pragma("unroll") for (int o_ = 0; o_ < 3; ++o_){               \
  unsigned pv_ = (unsigned)f2bf(g##S[o_][0]) | ((unsigned)f2bf(g##S[o_][1]) << 16);       \
  *(unsigned*)(lds + (BUF) + awr + (o_ << 9)) = pv_; } }while(0)

// phase-split K-step (m201 template): issue ds_reads + stages + gathers, barrier,
// lgkm(0) + sched fence (rule #18), prio-wrapped MFMA cluster, cvt-write, counted
// vmcnt + lgkm(0), barrier.
#define PSTEP(ABUF, WRBUF, WWBUF, KSN, GS, GP, GF, CS, CBUF, DO_G, DO_W, DO_C, VN) do{    \
  bf16x8 af_[6], bw_[4];                                                                  \
  _Pragma("unroll") for (int fm_ = 0; fm_ < 6; ++fm_)                                     \
    af_[fm_] = *(const bf16x8*)(lds + (ABUF) + ard + fm_*256);                            \
  _Pragma("unroll") for (int cn_ = 0; cn_ < 4; ++cn_)                                     \
    bw_[cn_] = *(const bf16x8*)(lds + (WRBUF) + wrd[cn_]);                                \
  if (DO_W) WSTAGE(WWBUF, KSN);                                                           \
  if (DO_G) GISS(GS, GP, GF);                                                             \
  __builtin_amdgcn_s_barrier();                                                           \
  asm volatile("s_waitcnt lgkmcnt(0)" ::: "memory");                                      \
  __builtin_amdgcn_sched_barrier(0);                                                      \
  __builtin_amdgcn_s_setprio(1);                                                          \
  _Pragma("unroll") for (int cn_ = 0; cn_ < 4; ++cn_)                                     \
  _Pragma("unroll") for (int fm_ = 0; fm_ < 6; ++fm_)                                     \
    acc[fm_][cn_] = __builtin_amdgcn_mfma_f32_16x16x32_bf16(af_[fm_], bw_[cn_], acc[fm_][cn_], 0, 0, 0); \
  __builtin_amdgcn_s_setprio(0);                                                          \
  if (DO_C) CVTWR(CS, CBUF);                                                              \
  asm volatile("s_waitcnt vmcnt(" #VN ") lgkmcnt(0)" ::: "memory");                       \
  __builtin_amdgcn_s_barrier();                                                           \
  asm volatile("" ::: "memory");                                                          \
}while(0)

#define A2SUB(ss, cc) do{                                                                 \
  bf16x8 a2[6];                                                                           \
  _Pragma("unroll") for (int fm = 0; fm < 6; ++fm){                                       \
    int byt = (((fm << 4) + lr) << 10) + ((ss) << 6) + (q << 4);                          \
    byt ^= (lr & 7) << 4;                                                                 \
    a2[fm] = *(const bf16x8*)(lds + byt);                                                 \
  }                                                                                       \
  _Pragma("unroll") for (int cn = 0; cn < 4; ++cn)                                        \
    _Pragma("unroll") for (int fm = 0; fm < 6; ++fm)                                      \
      acc2[fm][cn] = __builtin_amdgcn_mfma_f32_16x16x32_bf16(a2[fm], cc[cn], acc2[fm][cn], 0, 0, 0); \
}while(0)

// Block = (b, 32-t tile): 256 blocks, 512 threads (8 waves). Each wave: [96m x 64n].
__global__ __launch_bounds__(512, 2)
void fused_kernel(const float* __restrict__ x,
                  const float* __restrict__ b1v,
                  const float* __restrict__ b2v,
                  const unsigned short* __restrict__ w1b,
                  const unsigned short* __restrict__ w2b,
                  float* __restrict__ out)
{
  __shared__ char lds[98304];
  const int bid = blockIdx.x;
  const int b   = bid >> 3;
  const int t0  = (bid & 7) << 5;

  const int tid  = threadIdx.x;
  const int w    = tid >> 6;
  const int lane = tid & 63;
  const int q    = lane >> 4;
  const int lr   = lane & 15;
  const int u    = tid >> 5;          // [0,16): k-pair index for gather
  const int tt   = tid & 31;          // t within tile for gather

  // gather source offsets: k = par*32 + 2u + e
  int poff[2][3][2];
#pragma unroll
  for (int par = 0; par < 2; ++par)
#pragma unroll
    for (int e = 0; e < 2; ++e){
      const int k = par * 32 + 2 * u + e;
      const int r = dR[k], c = dC[k];
#pragma unroll
      for (int o = 0; o < 3; ++o){
        const int v = o - 1;                         // mean over o is order-free
        poff[par][o][e] = ((((r - v) & 15) << 4) | ((c - v) & 15)) << 8;
      }
    }
  const float* xb = x + (((long)b << 21) + t0 + tt);

  // A-tile: [kb4][row96][16B], kb stride 1536
  const int awr = ((u >> 2) * 1536) + (tt << 4) + ((u & 3) << 2);   // + o*512
  const int ard = q * 1536 + (lr << 4);                              // + fm*256
  // W-frag read: [col][4 slot][16B], slot = q ^ ((col>>1)&3)
  int wrd[4];
#pragma unroll
  for (int cn = 0; cn < 4; ++cn){
    const int col = (w << 6) + (cn << 4) + lr;
    wrd[cn] = col * 64 + ((q ^ ((col >> 1) & 3)) << 4);
  }
  // W stage: linear LDS dest (wave-uniform), inverse-swizzled packed global source
  int wso[4], wdb[4];
#pragma unroll
  for (int i = 0; i < 4; ++i){
    const int colb = (w << 6) + (i << 4);
    const int col  = colb + (lane >> 2);
    wso[i] = col * 64 + (((lane & 3) ^ ((col >> 1) & 3)) << 4);
    wdb[i] = colb * 64;
  }
  float b1c[4];
#pragma unroll
  for (int cn = 0; cn < 4; ++cn) b1c[cn] = b1v[(w << 6) + (cn << 4) + lr];

  f32x4 acc[6][4];
#pragma unroll
  for (int fm = 0; fm < 6; ++fm)
#pragma unroll
    for (int cn = 0; cn < 4; ++cn)
      acc[fm][cn] = f32x4{0.f, 0.f, 0.f, 0.f};

  float g0[3][2], g1[3][2];

  // ---------------- prologue ----------------
  // tile0 -> LA0 directly; W0 -> LW0; g1 <- tile1 in flight; counted drain.
  {
    float gp[3][2];
#pragma unroll
    for (int o_ = 0; o_ < 3; ++o_)
#pragma unroll
      for (int e_ = 0; e_ < 2; ++e_)
        gp[o_][e_] = xb[poff[0][o_][e_]];          // tile 0 (f=0, par=0)
    WSTAGE(LW0, 0);                                // W k-step 0
    GISS(1, 1, 0);                                 // tile 1 (f=0, par=1)
#pragma unroll
    for (int o_ = 0; o_ < 3; ++o_){
      unsigned pv_ = (unsigned)f2bf(gp[o_][0]) | ((unsigned)f2bf(gp[o_][1]) << 16);
      *(unsigned*)(lds + LA0 + awr + (o_ << 9)) = pv_;
    }
    asm volatile("s_waitcnt vmcnt(6) lgkmcnt(0)" ::: "memory");   // W0 done, g1 in flight
    __builtin_amdgcn_s_barrier();
    asm volatile("" ::: "memory");
  }

  // ---------------- phase 1: 64 K-steps, double-barrier phase schedule ----------
  // step N: ds_read (LA,LW)[N%2]; stage W(N+1)->LW[(N+1)%2]; issue gather tile N+2
  //         (slot N%2); MFMA; cvt tile N+1 (slot (N+1)%2) -> LA[(N+1)%2].
#pragma unroll 1
  for (int it = 0; it < 31; ++it){
    PSTEP(LA0, LW0, LW1, (it << 1) + 1, 0, 0, it + 1, 1, LA1, 1, 1, 1, 6);  // even step 2it
    PSTEP(LA1, LW1, LW0, (it << 1) + 2, 1, 1, it + 1, 0, LA0, 1, 1, 1, 6);  // odd step 2it+1
  }
  PSTEP(LA0, LW0, LW1, 63, 0, 0, 0, 1, LA1, 0, 1, 1, 0);   // step 62: stage W63, cvt tile63
  PSTEP(LA1, LW1, LW0,  0, 0, 0, 0, 0, LA0, 0, 0, 0, 0);   // step 63: compute only

  // ---------------- epilogue 1: bias + leaky -> A1 bf16 (XOR-swizzled) --------
#pragma unroll
  for (int cn = 0; cn < 4; ++cn){
    const int h  = (w << 6) + (cn << 4) + lr;
#pragma unroll
    for (int fm = 0; fm < 6; ++fm)
#pragma unroll
      for (int r = 0; r < 4; ++r){
        float vv = acc[fm][cn][r] + b1c[cn];
        vv = vv > 0.f ? vv : 0.01f * vv;
        const int row = (fm << 4) + (q << 2) + r;    // D row = 4*(lane>>4)+reg
        int byt = (row << 10) + (h << 1);
        byt ^= (row & 7) << 4;
        *(unsigned short*)(lds + byt) = f2bf(vv);
      }
  }
  asm volatile("s_waitcnt lgkmcnt(0)" ::: "memory");
  __builtin_amdgcn_s_barrier();
  asm volatile("" ::: "memory");

  // ---------------- phase 2: K=512 vs packed W2 (L2 reg frags), barrier-free ----
  int w2off[4];
  float b2c[4];
#pragma unroll
  for (int cn = 0; cn < 4; ++cn){
    const int col = (w << 6) + (cn << 4) + lr;
    w2off[cn] = (col << 6) + (q << 4);
    b2c[cn] = b2v[col];
  }
  const char* w2c = (const char*)w2b;
  f32x4 acc2[6][4];
#pragma unroll
  for (int fm = 0; fm < 6; ++fm)
#pragma unroll
    for (int cn = 0; cn < 4; ++cn)
      acc2[fm][cn] = f32x4{0.f, 0.f, 0.f, 0.f};

  bf16x8 c0[4], c1[4];
#pragma unroll
  for (int cn = 0; cn < 4; ++cn) c0[cn] = *(const bf16x8*)(w2c + w2off[cn]);

#pragma unroll 1
  for (int it2 = 0; it2 < 8; ++it2){
    const int s0 = it2 << 1;
#pragma unroll
    for (int cn = 0; cn < 4; ++cn)
      c1[cn] = *(const bf16x8*)(w2c + (((long)(s0 + 1)) << 15) + w2off[cn]);
    A2SUB(s0, c0);
    if (it2 < 7){
#pragma unroll
      for (int cn = 0; cn < 4; ++cn)
        c0[cn] = *(const bf16x8*)(w2c + (((long)(s0 + 2)) << 15) + w2off[cn]);
    }
    A2SUB(s0 + 1, c1);
  }

  // ---------------- epilogue 2: bias + leaky + mean(o) -> [B,H,T] -------------
#pragma unroll
  for (int cn = 0; cn < 4; ++cn){
    const int h  = (w << 6) + (cn << 4) + lr;
#pragma unroll
    for (int p = 0; p < 2; ++p){
      f32x4 ov;
#pragma unroll
      for (int r = 0; r < 4; ++r){
        float s = 0.f;
#pragma unroll
        for (int oo = 0; oo < 3; ++oo){
          float vv = acc2[oo * 2 + p][cn][r] + b2c[cn];
          vv = vv > 0.f ? vv : 0.01f * vv;
          s += vv;
        }
        ov[r] = s * (1.f / 3.f);
      }
      *(f32x4*)(out + (((long)b * 512 + h) << 8) + t0 + (p << 4) + (q << 2)) = ov;
    }
  }
}

extern "C" void kernel_launch(void* const* d_in, const int* in_sizes, int n_in,
                              void* d_out, int out_size, void* d_ws, size_t ws_size,
                              hipStream_t stream){
  const float* x  = (const float*)d_in[0];
  const float* w1 = (const float*)d_in[1];
  const float* b1 = (const float*)d_in[2];
  const float* w2 = (const float*)d_in[3];
  const float* b2 = (const float*)d_in[4];
  unsigned short* w1b = (unsigned short*)d_ws;            // packed W1: 2 MiB
  unsigned short* w2b = w1b + 512 * 2048;                 // packed W2: 0.5 MiB
  conv_w_kernel<<<1280, 256, 0, stream>>>(w1, w2, w1b, w2b);
  fused_kernel<<<256, 512, 0, stream>>>(x, b1, b2, w1b, w2b, (float*)d_out);
}

// Round 19
// 79.932 us; speedup vs baseline: 1.0459x; 1.0022x over previous
//
#include <hip/hip_runtime.h>
#include <stdint.h>

typedef __attribute__((ext_vector_type(8))) __bf16 bf16x8;
typedef __attribute__((ext_vector_type(4))) float f32x4;

// Selected upper-tri circular-adjacency pairs (r,c), row-major triu order. K=64.
__device__ const unsigned char dR[64] = {
  0,0,0,0,0,0,0,
  1,1,1,1,1,1,
  2,2,2,2,2,
  3,3,3,3,
  4,4,4,4,
  5,5,5,5,
  6,6,6,6,
  7,7,7,7,
  8,8,8,8,
  9,9,9,9,
  10,10,10,10,
  11,11,11,11,
  12,12,12,12,
  13,13,13,
  14,14,
  15};
__device__ const unsigned char dC[64] = {
  0,1,2,3,13,14,15,
  1,2,3,4,14,15,
  2,3,4,5,15,
  3,4,5,6,
  4,5,6,7,
  5,6,7,8,
  6,7,8,9,
  7,8,9,10,
  8,9,10,11,
  9,10,11,12,
  10,11,12,13,
  11,12,13,14,
  12,13,14,15,
  13,14,15,
  14,15,
  15};

__device__ __forceinline__ unsigned short f2bf(float x){
  unsigned u = __builtin_bit_cast(unsigned, x);
  return (unsigned short)((u + 0x7FFFu + ((u >> 16) & 1u)) >> 16);
}

__device__ __forceinline__ void gl16(const void* g, void* l){
  __builtin_amdgcn_global_load_lds((const __attribute__((address_space(1))) unsigned int*)g,
                                   (__attribute__((address_space(3))) unsigned int*)l,
                                   16, 0, 0);
}

// fp32 -> bf16 conversion + K-STEP PACKING: W1 -> [64 ks][512 col][32 k] bf16,
// W2 -> [16 ks][512 col][32 k] bf16. Contiguous 1KB per (ks, 16-col chunk).
__global__ void conv_w_kernel(const float* __restrict__ w1, const float* __restrict__ w2,
                              unsigned short* __restrict__ o1, unsigned short* __restrict__ o2){
  int i = blockIdx.x * 256 + threadIdx.x;
  if (i < 262144){                                  // W1: [512][2048] fp32, float4 idx
    float4 v = ((const float4*)w1)[i];
    ushort4 pk; pk.x=f2bf(v.x); pk.y=f2bf(v.y); pk.z=f2bf(v.z); pk.w=f2bf(v.w);
    const int col = i >> 9;
    const int kb  = (i & 511) << 2;
    const int ks  = kb >> 5, ko = kb & 31;
    ((ushort4*)o1)[(ks << 12) + (col << 3) + (ko >> 2)] = pk;
  } else {
    int j = i - 262144;
    if (j < 65536){                                 // W2: [512][512] fp32
      float4 v = ((const float4*)w2)[j];
      ushort4 pk; pk.x=f2bf(v.x); pk.y=f2bf(v.y); pk.z=f2bf(v.z); pk.w=f2bf(v.w);
      const int col = j >> 7;
      const int kb  = (j & 127) << 2;
      const int ks  = kb >> 5, ko = kb & 31;
      ((ushort4*)o2)[(ks << 12) + (col << 3) + (ko >> 2)] = pk;
    }
  }
}

// LDS: phase 1: W dbuf 2x32KB @ 0/32768 ([512 col][4 slot][16B], slot-swizzled),
//               gather A dbuf 2x6144 @ 65536/71680 ([kb4][96 row][16B]).
//      phase 2: A1 [96 row][512 h] bf16 XOR-swizzled @ [0, 98304) (aliases, post-barrier)
#define LW0 0
#define LW1 32768
#define LA0 65536
#define LA1 71680

// stage W k-step KS into buffer WBUF (wave-private 64 cols, 4 x gl16, packed source)
#define WSTAGE(WBUF, KS) do{ _Pragma("unroll") for (int i_ = 0; i_ < 4; ++i_)             \
  gl16((const char*)w1b + (((long)(KS)) << 15) + wso[i_], lds + (WBUF) + wdb[i_]); }while(0)

// issue 6 gather register loads into static slot S (parity PAR fixed per slot)
#define GISS(S, PAR, FV) do{ const float* xf_ = xb + ((long)(FV) << 16);                  \
  _Pragma("unroll") for (int o_ = 0; o_ < 3; ++o_)                                        \
  _Pragma("unroll") for (int e_ = 0; e_ < 2; ++e_)                                        \
    g##S[o_][e_] = xf_[poff[PAR][o_][e_]]; }while(0)

// cvt slot -> ds_write A-tile into buffer BUF (compiler inserts counted vmcnt for g regs)
#define CVTWR(S, BUF) do{ _Pragma("unroll") for (int o_ = 0; o_ < 3; ++o_){               \
  unsigned pv_ = (unsigned)f2bf(g##S[o_][0]) | ((unsigned)f2bf(g##S[o_][1]) << 16);       \
  *(unsigned*)(lds + (BUF) + awr + (o_ << 9)) = pv_; } }while(0)

// phase-split K-step: issue ds_reads + stages + gathers, barrier, window pin
// (sched_barrier only — NO explicit lgkm drain: compiler emits fine-grained counted
// lgkmcnt before each MFMA use, letting early MFMAs overlap the tail ds_reads),
// prio-wrapped MFMA cluster, cvt-write, counted vmcnt + lgkm(0) close, barrier.
#define PSTEP(ABUF, WRBUF, WWBUF, KSN, GS, GP, GF, CS, CBUF, DO_G, DO_W, DO_C, VN) do{    \
  bf16x8 af_[6], bw_[4];                                                                  \
  _Pragma("unroll") for (int fm_ = 0; fm_ < 6; ++fm_)                                     \
    af_[fm_] = *(const bf16x8*)(lds + (ABUF) + ard + fm_*256);                            \
  _Pragma("unroll") for (int cn_ = 0; cn_ < 4; ++cn_)                                     \
    bw_[cn_] = *(const bf16x8*)(lds + (WRBUF) + wrd[cn_]);                                \
  if (DO_W) WSTAGE(WWBUF, KSN);                                                           \
  if (DO_G) GISS(GS, GP, GF);                                                             \
  __builtin_amdgcn_s_barrier();                                                           \
  __builtin_amdgcn_sched_barrier(0);                                                      \
  __builtin_amdgcn_s_setprio(1);                                                          \
  _Pragma("unroll") for (int cn_ = 0; cn_ < 4; ++cn_)                                     \
  _Pragma("unroll") for (int fm_ = 0; fm_ < 6; ++fm_)                                     \
    acc[fm_][cn_] = __builtin_amdgcn_mfma_f32_16x16x32_bf16(af_[fm_], bw_[cn_], acc[fm_][cn_], 0, 0, 0); \
  __builtin_amdgcn_s_setprio(0);                                                          \
  if (DO_C) CVTWR(CS, CBUF);                                                              \
  asm volatile("s_waitcnt vmcnt(" #VN ") lgkmcnt(0)" ::: "memory");                       \
  __builtin_amdgcn_s_barrier();                                                           \
  asm volatile("" ::: "memory");                                                          \
}while(0)

#define A2SUB(ss, cc) do{                                                                 \
  bf16x8 a2[6];                                                                           \
  _Pragma("unroll") for (int fm = 0; fm < 6; ++fm){                                       \
    int byt = (((fm << 4) + lr) << 10) + ((ss) << 6) + (q << 4);                          \
    byt ^= (lr & 7) << 4;                                                                 \
    a2[fm] = *(const bf16x8*)(lds + byt);                                                 \
  }                                                                                       \
  _Pragma("unroll") for (int cn = 0; cn < 4; ++cn)                                        \
    _Pragma("unroll") for (int fm = 0; fm < 6; ++fm)                                      \
      acc2[fm][cn] = __builtin_amdgcn_mfma_f32_16x16x32_bf16(a2[fm], cc[cn], acc2[fm][cn], 0, 0, 0); \
}while(0)

// Block = (b, 32-t tile): 256 blocks, 512 threads (8 waves). Each wave: [96m x 64n].
__global__ __launch_bounds__(512, 2)
void fused_kernel(const float* __restrict__ x,
                  const float* __restrict__ b1v,
                  const float* __restrict__ b2v,
                  const unsigned short* __restrict__ w1b,
                  const unsigned short* __restrict__ w2b,
                  float* __restrict__ out)
{
  __shared__ char lds[98304];
  const int bid = blockIdx.x;
  const int b   = bid >> 3;
  const int t0  = (bid & 7) << 5;

  const int tid  = threadIdx.x;
  const int w    = tid >> 6;
  const int lane = tid & 63;
  const int q    = lane >> 4;
  const int lr   = lane & 15;
  const int u    = tid >> 5;          // [0,16): k-pair index for gather
  const int tt   = tid & 31;          // t within tile for gather

  // gather source offsets: k = par*32 + 2u + e
  int poff[2][3][2];
#pragma unroll
  for (int par = 0; par < 2; ++par)
#pragma unroll
    for (int e = 0; e < 2; ++e){
      const int k = par * 32 + 2 * u + e;
      const int r = dR[k], c = dC[k];
#pragma unroll
      for (int o = 0; o < 3; ++o){
        const int v = o - 1;                         // mean over o is order-free
        poff[par][o][e] = ((((r - v) & 15) << 4) | ((c - v) & 15)) << 8;
      }
    }
  const float* xb = x + (((long)b << 21) + t0 + tt);

  // A-tile: [kb4][row96][16B], kb stride 1536
  const int awr = ((u >> 2) * 1536) + (tt << 4) + ((u & 3) << 2);   // + o*512
  const int ard = q * 1536 + (lr << 4);                              // + fm*256
  // W-frag read: [col][4 slot][16B], slot = q ^ ((col>>1)&3)
  int wrd[4];
#pragma unroll
  for (int cn = 0; cn < 4; ++cn){
    const int col = (w << 6) + (cn << 4) + lr;
    wrd[cn] = col * 64 + ((q ^ ((col >> 1) & 3)) << 4);
  }
  // W stage: linear LDS dest (wave-uniform), inverse-swizzled packed global source
  int wso[4], wdb[4];
#pragma unroll
  for (int i = 0; i < 4; ++i){
    const int colb = (w << 6) + (i << 4);
    const int col  = colb + (lane >> 2);
    wso[i] = col * 64 + (((lane & 3) ^ ((col >> 1) & 3)) << 4);
    wdb[i] = colb * 64;
  }
  float b1c[4];
#pragma unroll
  for (int cn = 0; cn < 4; ++cn) b1c[cn] = b1v[(w << 6) + (cn << 4) + lr];

  f32x4 acc[6][4];
#pragma unroll
  for (int fm = 0; fm < 6; ++fm)
#pragma unroll
    for (int cn = 0; cn < 4; ++cn)
      acc[fm][cn] = f32x4{0.f, 0.f, 0.f, 0.f};

  float g0[3][2], g1[3][2];

  // ---------------- prologue ----------------
  // tile0 -> LA0 directly; W0 -> LW0; g1 <- tile1 in flight; counted drain.
  {
    float gp[3][2];
#pragma unroll
    for (int o_ = 0; o_ < 3; ++o_)
#pragma unroll
      for (int e_ = 0; e_ < 2; ++e_)
        gp[o_][e_] = xb[poff[0][o_][e_]];          // tile 0 (f=0, par=0)
    WSTAGE(LW0, 0);                                // W k-step 0
    GISS(1, 1, 0);                                 // tile 1 (f=0, par=1)
#pragma unroll
    for (int o_ = 0; o_ < 3; ++o_){
      unsigned pv_ = (unsigned)f2bf(gp[o_][0]) | ((unsigned)f2bf(gp[o_][1]) << 16);
      *(unsigned*)(lds + LA0 + awr + (o_ << 9)) = pv_;
    }
    asm volatile("s_waitcnt vmcnt(6) lgkmcnt(0)" ::: "memory");   // W0 done, g1 in flight
    __builtin_amdgcn_s_barrier();
    asm volatile("" ::: "memory");
  }

  // ---------------- phase 1: 64 K-steps, double-barrier phase schedule ----------
  // step N: ds_read (LA,LW)[N%2]; stage W(N+1)->LW[(N+1)%2]; issue gather tile N+2
  //         (slot N%2); MFMA (compiler-counted lgkm waits); cvt tile N+1 -> LA[(N+1)%2].
#pragma unroll 1
  for (int it = 0; it < 31; ++it){
    PSTEP(LA0, LW0, LW1, (it << 1) + 1, 0, 0, it + 1, 1, LA1, 1, 1, 1, 6);  // even step 2it
    PSTEP(LA1, LW1, LW0, (it << 1) + 2, 1, 1, it + 1, 0, LA0, 1, 1, 1, 6);  // odd step 2it+1
  }
  PSTEP(LA0, LW0, LW1, 63, 0, 0, 0, 1, LA1, 0, 1, 1, 0);   // step 62: stage W63, cvt tile63
  PSTEP(LA1, LW1, LW0,  0, 0, 0, 0, 0, LA0, 0, 0, 0, 0);   // step 63: compute only

  // ---------------- epilogue 1: bias + leaky -> A1 bf16 (XOR-swizzled) --------
#pragma unroll
  for (int cn = 0; cn < 4; ++cn){
    const int h  = (w << 6) + (cn << 4) + lr;
#pragma unroll
    for (int fm = 0; fm < 6; ++fm)
#pragma unroll
      for (int r = 0; r < 4; ++r){
        float vv = acc[fm][cn][r] + b1c[cn];
        vv = vv > 0.f ? vv : 0.01f * vv;
        const int row = (fm << 4) + (q << 2) + r;    // D row = 4*(lane>>4)+reg
        int byt = (row << 10) + (h << 1);
        byt ^= (row & 7) << 4;
        *(unsigned short*)(lds + byt) = f2bf(vv);
      }
  }
  asm volatile("s_waitcnt lgkmcnt(0)" ::: "memory");
  __builtin_amdgcn_s_barrier();
  asm volatile("" ::: "memory");

  // ---------------- phase 2: K=512 vs packed W2 (L2 reg frags), barrier-free ----
  int w2off[4];
  float b2c[4];
#pragma unroll
  for (int cn = 0; cn < 4; ++cn){
    const int col = (w << 6) + (cn << 4) + lr;
    w2off[cn] = (col << 6) + (q << 4);
    b2c[cn] = b2v[col];
  }
  const char* w2c = (const char*)w2b;
  f32x4 acc2[6][4];
#pragma unroll
  for (int fm = 0; fm < 6; ++fm)
#pragma unroll
    for (int cn = 0; cn < 4; ++cn)
      acc2[fm][cn] = f32x4{0.f, 0.f, 0.f, 0.f};

  bf16x8 c0[4], c1[4];
#pragma unroll
  for (int cn = 0; cn < 4; ++cn) c0[cn] = *(const bf16x8*)(w2c + w2off[cn]);

#pragma unroll 1
  for (int it2 = 0; it2 < 8; ++it2){
    const int s0 = it2 << 1;
#pragma unroll
    for (int cn = 0; cn < 4; ++cn)
      c1[cn] = *(const bf16x8*)(w2c + (((long)(s0 + 1)) << 15) + w2off[cn]);
    A2SUB(s0, c0);
    if (it2 < 7){
#pragma unroll
      for (int cn = 0; cn < 4; ++cn)
        c0[cn] = *(const bf16x8*)(w2c + (((long)(s0 + 2)) << 15) + w2off[cn]);
    }
    A2SUB(s0 + 1, c1);
  }

  // ---------------- epilogue 2: bias + leaky + mean(o) -> [B,H,T] -------------
#pragma unroll
  for (int cn = 0; cn < 4; ++cn){
    const int h  = (w << 6) + (cn << 4) + lr;
#pragma unroll
    for (int p = 0; p < 2; ++p){
      f32x4 ov;
#pragma unroll
      for (int r = 0; r < 4; ++r){
        float s = 0.f;
#pragma unroll
        for (int oo = 0; oo < 3; ++oo){
          float vv = acc2[oo * 2 + p][cn][r] + b2c[cn];
          vv = vv > 0.f ? vv : 0.01f * vv;
          s += vv;
        }
        ov[r] = s * (1.f / 3.f);
      }
      *(f32x4*)(out + (((long)b * 512 + h) << 8) + t0 + (p << 4) + (q << 2)) = ov;
    }
  }
}

extern "C" void kernel_launch(void* const* d_in, const int* in_sizes, int n_in,
                              void* d_out, int out_size, void* d_ws, size_t ws_size,
                              hipStream_t stream){
  const float* x  = (const float*)d_in[0];
  const float* w1 = (const float*)d_in[1];
  const float* b1 = (const float*)d_in[2];
  const float* w2 = (const float*)d_in[3];
  const float* b2 = (const float*)d_in[4];
  unsigned short* w1b = (unsigned short*)d_ws;            // packed W1: 2 MiB
  unsigned short* w2b = w1b + 512 * 2048;                 // packed W2: 0.5 MiB
  conv_w_kernel<<<1280, 256, 0, stream>>>(w1, w2, w1b, w2b);
  fused_kernel<<<256, 512, 0, stream>>>(x, b1, b2, w1b, w2b, (float*)d_out);
}